// Round 3
// baseline (571.447 us; speedup 1.0000x reference)
//
#include <hip/hip_runtime.h>

// CapsNet dynamic routing, B=256, P=2048, C=10, OUT=16, IN=8, 3 iters.
// R9: recompute-uhat structure (R8) rescheduled for latency:
//  - BT=16, PT=32, lane=(b_l, h, oh): acc/uh are [5c][8o] (half the regs of R8),
//    softmax couples oh via shfl_xor(.,1) and h via shfl_xor(.,2).
//  - W chunks (4p x 5KB) staged with global_load_lds width-16, DOUBLE-buffered:
//    one barrier per chunk, next chunk's DMA in flight under current compute.
//  - u tile lives in registers (per-chunk float4 prefetch) -> no uL array.
//  - LDS 51.8KB -> 3 blocks/CU (was 2 at 58KB); MODE0 elides vL -> 40KB.
//  - Bank audit (R8 had 13.2M conflicts from sAcc stride 160 = 32-way):
//    vL stride (b,h)=85 / kc=17 -> 2-way (free); sAcc stride 161 -> 2-way;
//    W broadcast reads <=4 distinct addrs/inst.
// Passes: K<0>: s1=sum_p uhat; K<1>: v1=squash(.1 s1), lg2=uhat.v1 -> global,
// s2+=softmax(lg2)*uhat; K<2>: v2=squash(s2), lg3=lg2+uhat.v2, s3+=...;
// k_out: squash(s3). s partials: regs -> sAcc turn-reduce -> fp32 atomicAdd.

#define Bn 256
#define Pn 2048
#define Cn 10
#define On 16
#define In 8
#define ROW 160
#define BT 16
#define PT 32
#define CHP 4
#define NCH (PT / CHP)   // 8 chunks
#define TPB 256
#define NW (TPB / 64)    // 4 waves
#define GRID ((Bn / BT) * (Pn / PT)) // 16*64 = 1024
#define WCH (CHP * Cn * On * In)     // 5120 floats per W chunk

__device__ __forceinline__ void gl_lds16(const float* g, float* l) {
  __builtin_amdgcn_global_load_lds(
      (const __attribute__((address_space(1))) unsigned int*)g,
      (__attribute__((address_space(3))) unsigned int*)l, 16, 0, 0);
}

template <int MODE>
__global__ __launch_bounds__(TPB, 3) void k_cap(const float* __restrict__ u,
                                                const float* __restrict__ W,
                                                const float* __restrict__ sPrev,
                                                float* __restrict__ sOut,
                                                float* __restrict__ lg) {
  __shared__ float wS[2][WCH];      // 40960 B; buf0 reused as sAcc at the end
  __shared__ float vL[BT * 2 * 85]; // 10880 B; [b][h][kc*17 + o], 2-way banks
  const int x = blockIdx.x;
  const int bt = x >> 6;  // 16 b-tiles
  const int pt = x & 63;  // 64 p-tiles; co-readers of a p-tile share XCD (mod 8)
  const int tid = threadIdx.x;
  const int lane = tid & 63;
  const int wid = tid >> 6;
  const int b_l = lane >> 2;
  const int h = (lane >> 1) & 1;
  const int oh = lane & 1;
  const int b0 = bt * BT;
  const int p0 = pt * PT;

  // ---- prologue: async W chunk0 -> buf0; u chunk0 -> regs ----
  {
    const float* ws0 = W + (size_t)p0 * 1280 + tid * 4;
#pragma unroll
    for (int r = 0; r < 5; ++r) gl_lds16(ws0 + r * 1024, &wS[0][tid * 4 + r * 1024]);
  }
  float4 ua[2], ub[2];
  {
    const float4* up = reinterpret_cast<const float4*>(
        u + ((size_t)(b0 + b_l) * Pn + p0 + wid) * In);
    ua[0] = up[0];
    ub[0] = up[1];
  }

  // ---- stage + squash v (MODE>=1); overlaps the chunk0 DMA ----
  if (MODE >= 1) {
#pragma unroll
    for (int r = 0; r < 10; ++r) {
      const int g = tid + 256 * r; // 2560 cells
      const int bl = g / 160, pos = g - 160 * bl;
      const int c = pos >> 4, o = pos & 15;
      const int hh = (c >= 5), cc = c - 5 * hh;
      vL[(bl * 2 + hh) * 85 + cc * 17 + o] = sPrev[(size_t)(b0 + bl) * ROW + pos];
    }
    __syncthreads();
    if (tid < BT * Cn) {
      const int bl = tid / 10, c = tid - 10 * bl;
      const int hh = (c >= 5), cc = c - 5 * hh;
      float* vp = &vL[(bl * 2 + hh) * 85 + cc * 17];
      float sq = 0.f;
#pragma unroll
      for (int o = 0; o < On; ++o) { const float xx = vp[o]; sq += xx * xx; }
      const float scale = (MODE == 1) ? 0.1f : 1.0f;
      sq *= scale * scale;
      const float fac = scale * (sq / (1.f + sq)) / sqrtf(sq + 1e-9f);
#pragma unroll
      for (int o = 0; o < On; ++o) vp[o] *= fac;
    }
  }
  __syncthreads(); // barrier drains vmcnt -> buf0 ready; vL visible

  float acc[5][8];
#pragma unroll
  for (int kc = 0; kc < 5; ++kc)
#pragma unroll
    for (int o = 0; o < 8; ++o) acc[kc][o] = 0.f;

  const int vbase = (b_l * 2 + h) * 85 + oh * 8;
  const int wbase = h * 5 * 128 + oh * 64;

#pragma unroll
  for (int ch = 0; ch < NCH; ++ch) {
    // prefetch chunk ch+1: async W DMA into other buf; u into regs
    if (ch + 1 < NCH) {
      const float* wsn = W + ((size_t)p0 + (ch + 1) * CHP) * 1280 + tid * 4;
#pragma unroll
      for (int r = 0; r < 5; ++r)
        gl_lds16(wsn + r * 1024, &wS[(ch + 1) & 1][tid * 4 + r * 1024]);
      const float4* up = reinterpret_cast<const float4*>(
          u + ((size_t)(b0 + b_l) * Pn + p0 + (ch + 1) * CHP + wid) * In);
      ua[(ch + 1) & 1] = up[0];
      ub[(ch + 1) & 1] = up[1];
    }
    const float uu[8] = {ua[ch & 1].x, ua[ch & 1].y, ua[ch & 1].z, ua[ch & 1].w,
                         ub[ch & 1].x, ub[ch & 1].y, ub[ch & 1].z, ub[ch & 1].w};
    const float* wp = &wS[ch & 1][wid * 1280 + wbase];

    if (MODE == 0) {
#pragma unroll
      for (int kc = 0; kc < 5; ++kc) {
        const float* wc = wp + kc * 128;
#pragma unroll
        for (int o = 0; o < 8; ++o) {
          const float* w8 = wc + o * 8;
          float d = w8[0] * uu[0];
#pragma unroll
          for (int i = 1; i < 8; ++i) d = __builtin_fmaf(w8[i], uu[i], d);
          acc[kc][o] += d;
        }
      }
    } else {
      const int p = p0 + ch * CHP + wid;
      float* lrow = lg + ((size_t)p * Bn + (b0 + b_l)) * Cn + h * 5;
      float lprev[5];
      if (MODE == 2) { // issue early: latency hides under the dot loop
#pragma unroll
        for (int kc = 0; kc < 5; ++kc) lprev[kc] = lrow[kc];
      }
      float uh[5][8], lgv[5];
#pragma unroll
      for (int kc = 0; kc < 5; ++kc) {
        const float* wc = wp + kc * 128;
        const float* vp = &vL[vbase + kc * 17];
        float ls = 0.f;
#pragma unroll
        for (int o = 0; o < 8; ++o) {
          const float* w8 = wc + o * 8;
          float d = w8[0] * uu[0];
#pragma unroll
          for (int i = 1; i < 8; ++i) d = __builtin_fmaf(w8[i], uu[i], d);
          uh[kc][o] = d;
          ls = __builtin_fmaf(d, vp[o], ls);
        }
        lgv[kc] = ls;
      }
#pragma unroll
      for (int kc = 0; kc < 5; ++kc) lgv[kc] += __shfl_xor(lgv[kc], 1, 64);
      if (MODE == 2) {
#pragma unroll
        for (int kc = 0; kc < 5; ++kc) lgv[kc] += lprev[kc];
      } else if (oh == 0) {
#pragma unroll
        for (int kc = 0; kc < 5; ++kc) lrow[kc] = lgv[kc];
      }
      float m = lgv[0];
#pragma unroll
      for (int kc = 1; kc < 5; ++kc) m = fmaxf(m, lgv[kc]);
      m = fmaxf(m, __shfl_xor(m, 2, 64));
      float e[5], ss = 0.f;
#pragma unroll
      for (int kc = 0; kc < 5; ++kc) { e[kc] = __expf(lgv[kc] - m); ss += e[kc]; }
      ss += __shfl_xor(ss, 2, 64);
      const float inv = 1.f / ss;
#pragma unroll
      for (int kc = 0; kc < 5; ++kc) {
        const float cv = e[kc] * inv;
#pragma unroll
        for (int o = 0; o < 8; ++o)
          acc[kc][o] = __builtin_fmaf(cv, uh[kc][o], acc[kc][o]);
      }
    }
    __syncthreads(); // current-buf readers done; next-chunk DMA drained
  }

  // ---- cross-wave reduce: sAcc = wS buf0, stride 161 (2-way banks) ----
  float* sAcc = &wS[0][0];
#pragma unroll
  for (int r = 0; r < NW; ++r) {
    __syncthreads();
    if (wid == r) {
      float* dst = &sAcc[b_l * 161 + h * 80 + oh * 8];
      if (r == 0) {
#pragma unroll
        for (int kc = 0; kc < 5; ++kc)
#pragma unroll
          for (int o = 0; o < 8; ++o) dst[kc * 16 + o] = acc[kc][o];
      } else {
#pragma unroll
        for (int kc = 0; kc < 5; ++kc)
#pragma unroll
          for (int o = 0; o < 8; ++o) dst[kc * 16 + o] += acc[kc][o];
      }
    }
  }
  __syncthreads();
#pragma unroll
  for (int r = 0; r < 10; ++r) {
    const int g = tid + 256 * r; // 2560
    const int bl = g / 160, rem = g - 160 * bl;
    atomicAdd(&sOut[(size_t)(b0 + bl) * ROW + rem], sAcc[bl * 161 + rem]);
  }
}

__global__ __launch_bounds__(256) void k_out(const float* __restrict__ s,
                                             float* __restrict__ out) {
  const int g = blockIdx.x * 256 + threadIdx.x; // [0, 2560) = (b,c)
  const int b = g / 10, c = g - 10 * b;
  const float* sp = s + (size_t)b * ROW + c * 16;
  float sq = 0.f;
#pragma unroll
  for (int o = 0; o < On; ++o) { const float xx = sp[o]; sq += xx * xx; }
  const float fac = (sq / (1.f + sq)) / sqrtf(sq + 1e-9f);
  float* op = out + (size_t)b * ROW + c * 16;
#pragma unroll
  for (int o = 0; o < On; ++o) op[o] = fac * sp[o];
}

extern "C" void kernel_launch(void* const* d_in, const int* in_sizes, int n_in,
                              void* d_out, int out_size, void* d_ws, size_t ws_size,
                              hipStream_t stream) {
  (void)in_sizes; (void)n_in; (void)out_size;
  const float* u = (const float*)d_in[0];
  const float* W = (const float*)d_in[1];
  float* out = (float*)d_out;
  float* s1 = (float*)d_ws;            // [256][160] fp32
  float* s2 = s1 + (size_t)Bn * ROW;
  float* s3 = s2 + (size_t)Bn * ROW;
  float* lg = s3 + (size_t)Bn * ROW;   // [2048][256][10] fp32, 21MB
  const size_t need = ((size_t)3 * Bn * ROW + (size_t)Pn * Bn * Cn) * sizeof(float);
  if (ws_size < need) return;
  hipMemsetAsync(d_ws, 0, (size_t)3 * Bn * ROW * sizeof(float), stream);
  k_cap<0><<<GRID, TPB, 0, stream>>>(u, W, s1, s1, lg);
  k_cap<1><<<GRID, TPB, 0, stream>>>(u, W, s1, s2, lg);
  k_cap<2><<<GRID, TPB, 0, stream>>>(u, W, s2, s3, lg);
  k_out<<<10, 256, 0, stream>>>(s3, out);
}

// Round 4
// 303.159 us; speedup vs baseline: 1.8850x; 1.8850x over previous
//
#include <hip/hip_runtime.h>

// CapsNet dynamic routing, B=256, P=2048, C=10, OUT=16, IN=8, 3 iters.
// R10: R9 (recompute-uhat, dbuf gl_lds W) minus its two pathologies:
//  (1) R9 spilled ~450MB/dispatch to scratch (WRITE 320MB, VGPR capped 84 with
//      ~120 live): uh[5][8] held across softmax + cross-barrier dbuf arrays.
//      Fix: two-pass recompute (pass A: lgv = (W.u).v only; softmax; pass B:
//      recompute W.u, acc += cv*d). No uh, no reg arrays with runtime index,
//      launch_bounds(256,2) so the cap is 256 not 85. FMA doubles in MODE1/2
//      (VALUBusy was 10% -> free).
//  (2) R9's W broadcast reads were 4-way bank conflicts (sub-bases h*640+oh*64
//      both = 0 mod 32; 4.0e7 conflicts). Fix: k_perm pre-permutes W in global
//      (gl_lds dest must stay linear -> swizzle the SOURCE) to
//      [(kc*8+o)*32 + (h*2+oh)*8 + i] per p: lane groups 8 banks apart,
//      ds_read_b128 pairs hit disjoint bank quads -> conflict-free.
// Layouts: vL [b][h] stride 85, kc stride 17 (scalar reads, ~2-way = free);
// sAcc stride 161 turn-reduce (2-way); lg [p][b][10] fp32.
// Passes: K<0>: s1=sum_p uhat; K<1>: v1=squash(.1*s1), lg2=uhat.v1 -> global,
// s2+=softmax(lg2)*uhat; K<2>: v2=squash(s2), lg3=lg2+uhat.v2, s3+=...;
// k_out: squash(s3). s partials: regs -> sAcc turn-reduce -> fp32 atomicAdd.

#define Bn 256
#define Pn 2048
#define Cn 10
#define On 16
#define In 8
#define ROW 160
#define BT 16
#define PT 32
#define CHP 4
#define NCH (PT / CHP)   // 8 chunks
#define TPB 256
#define NW (TPB / 64)    // 4 waves
#define GRID ((Bn / BT) * (Pn / PT)) // 16*64 = 1024
#define WCH (CHP * Cn * On * In)     // 5120 floats per W chunk

__device__ __forceinline__ void gl_lds16(const float* g, float* l) {
  __builtin_amdgcn_global_load_lds(
      (const __attribute__((address_space(1))) unsigned int*)g,
      (__attribute__((address_space(3))) unsigned int*)l, 16, 0, 0);
}

__device__ __forceinline__ float dot8(float4 wa, float4 wb, float4 xa, float4 xb) {
  float d = wa.x * xa.x;
  d = __builtin_fmaf(wa.y, xa.y, d);
  d = __builtin_fmaf(wa.z, xa.z, d);
  d = __builtin_fmaf(wa.w, xa.w, d);
  d = __builtin_fmaf(wb.x, xb.x, d);
  d = __builtin_fmaf(wb.y, xb.y, d);
  d = __builtin_fmaf(wb.z, xb.z, d);
  d = __builtin_fmaf(wb.w, xb.w, d);
  return d;
}

// ---- one-time W permutation: per p, dst[(kc*8+o)*32 + g*8 + i] = W[p][c][o][i],
// c = (g>>1)*5 + kc, o_global = (g&1)*8 + o. Coalesced writes, gathered reads.
__global__ __launch_bounds__(256) void k_perm(const float* __restrict__ W,
                                              float* __restrict__ Wp) {
  const int p = blockIdx.x;
  const float* src = W + (size_t)p * 1280;
  float* dst = Wp + (size_t)p * 1280;
#pragma unroll
  for (int r = 0; r < 5; ++r) {
    const int w = threadIdx.x + 256 * r;
    const int q = w >> 5, rm = w & 31;
    const int g = rm >> 3, i = rm & 7;
    const int h = g >> 1, oh = g & 1;
    const int kc = q >> 3, ol = q & 7;
    dst[w] = src[(h * 5 + kc) * 128 + (oh * 8 + ol) * 8 + i];
  }
}

template <int MODE>
__global__ __launch_bounds__(TPB, 2) void k_cap(const float* __restrict__ u,
                                                const float* __restrict__ Wp,
                                                const float* __restrict__ sPrev,
                                                float* __restrict__ sOut,
                                                float* __restrict__ lg) {
  __shared__ float wS[2][WCH];      // 40960 B; buf0 reused as sAcc at the end
  __shared__ float vL[BT * 2 * 85]; // 10880 B; [b][h][kc*17 + o]
  const int x = blockIdx.x;
  const int bt = x >> 6;  // 16 b-tiles
  const int pt = x & 63;  // 64 p-tiles; sharers of a p-tile on one XCD (mod 8)
  const int tid = threadIdx.x;
  const int lane = tid & 63;
  const int wid = tid >> 6;
  const int b_l = lane >> 2;
  const int h = (lane >> 1) & 1;
  const int oh = lane & 1;
  const int b0 = bt * BT;
  const int p0 = pt * PT;

  // ---- prologue: async W chunk0 -> buf0; u chunk0 -> regs ----
  const float* wsrc = Wp + (size_t)p0 * 1280 + tid * 4;
#pragma unroll
  for (int r = 0; r < 5; ++r) gl_lds16(wsrc + r * 1024, &wS[0][tid * 4 + r * 1024]);

  const float* urow = u + ((size_t)(b0 + b_l) * Pn + p0) * In;
  float4 cua, cub;
  {
    const float4* up = reinterpret_cast<const float4*>(urow + wid * In);
    cua = up[0];
    cub = up[1];
  }

  // ---- stage + squash v (MODE>=1); overlaps the chunk0 DMA ----
  if (MODE >= 1) {
#pragma unroll
    for (int r = 0; r < 10; ++r) {
      const int g = tid + 256 * r; // 2560 cells
      const int bl = g / 160, pos = g - 160 * bl;
      const int c = pos >> 4, o = pos & 15;
      const int hh = (c >= 5), cc = c - 5 * hh;
      vL[(bl * 2 + hh) * 85 + cc * 17 + o] = sPrev[(size_t)(b0 + bl) * ROW + pos];
    }
    __syncthreads();
    if (tid < BT * Cn) {
      const int bl = tid / 10, c = tid - 10 * bl;
      const int hh = (c >= 5), cc = c - 5 * hh;
      float* vp = &vL[(bl * 2 + hh) * 85 + cc * 17];
      float sq = 0.f;
#pragma unroll
      for (int o = 0; o < On; ++o) { const float xx = vp[o]; sq += xx * xx; }
      const float scale = (MODE == 1) ? 0.1f : 1.0f;
      sq *= scale * scale;
      const float fac = scale * (sq / (1.f + sq)) / sqrtf(sq + 1e-9f);
#pragma unroll
      for (int o = 0; o < On; ++o) vp[o] *= fac;
    }
  }
  __syncthreads(); // drains vmcnt -> buf0 ready; vL visible

  float acc[5][8];
#pragma unroll
  for (int kc = 0; kc < 5; ++kc)
#pragma unroll
    for (int o = 0; o < 8; ++o) acc[kc][o] = 0.f;

  const int vbase = (b_l * 2 + h) * 85;
  const int wlane = (h * 2 + oh) * 8; // permuted-W lane-group base: 8 banks apart

  const float* bufC = &wS[0][0];
  float* bufN = &wS[1][0];
  for (int ch = 0; ch < NCH; ++ch) {
    // prefetch chunk ch+1 (named regs, no arrays -> no scratch)
    float4 nua = cua, nub = cub;
    if (ch + 1 < NCH) {
      const float* wn = wsrc + (size_t)(ch + 1) * WCH;
#pragma unroll
      for (int r = 0; r < 5; ++r) gl_lds16(wn + r * 1024, &bufN[tid * 4 + r * 1024]);
      const float4* up =
          reinterpret_cast<const float4*>(urow + ((ch + 1) * CHP + wid) * In);
      nua = up[0];
      nub = up[1];
    }
    const float* wp = bufC + wid * 1280 + wlane;

    if (MODE == 0) {
#pragma unroll
      for (int kc = 0; kc < 5; ++kc)
#pragma unroll
        for (int o = 0; o < 8; ++o) {
          const float4* w4 = reinterpret_cast<const float4*>(wp + (kc * 8 + o) * 32);
          acc[kc][o] += dot8(w4[0], w4[1], cua, cub);
        }
    } else {
      const int p = p0 + ch * CHP + wid;
      float* lrow = lg + ((size_t)p * Bn + (b0 + b_l)) * Cn + h * 5;
      float lprev[5];
      if (MODE == 2) { // issue early: latency hides under pass A
#pragma unroll
        for (int kc = 0; kc < 5; ++kc) lprev[kc] = lrow[kc];
      }
      // ---- pass A: logits only (no uh kept) ----
      float lgv[5];
#pragma unroll
      for (int kc = 0; kc < 5; ++kc) {
        const float* vp = &vL[vbase + kc * 17 + oh * 8];
        float ls = 0.f;
#pragma unroll
        for (int o = 0; o < 8; ++o) {
          const float4* w4 = reinterpret_cast<const float4*>(wp + (kc * 8 + o) * 32);
          ls = __builtin_fmaf(dot8(w4[0], w4[1], cua, cub), vp[o], ls);
        }
        lgv[kc] = ls;
      }
#pragma unroll
      for (int kc = 0; kc < 5; ++kc) lgv[kc] += __shfl_xor(lgv[kc], 1, 64);
      if (MODE == 2) {
#pragma unroll
        for (int kc = 0; kc < 5; ++kc) lgv[kc] += lprev[kc];
      } else if (oh == 0) {
#pragma unroll
        for (int kc = 0; kc < 5; ++kc) lrow[kc] = lgv[kc];
      }
      // softmax over 10 c's: 5 in-lane + cross-half (h) via shfl_xor 2
      float m = lgv[0];
#pragma unroll
      for (int kc = 1; kc < 5; ++kc) m = fmaxf(m, lgv[kc]);
      m = fmaxf(m, __shfl_xor(m, 2, 64));
      float e[5], ss = 0.f;
#pragma unroll
      for (int kc = 0; kc < 5; ++kc) { e[kc] = __expf(lgv[kc] - m); ss += e[kc]; }
      ss += __shfl_xor(ss, 2, 64);
      const float inv = 1.f / ss;
      // ---- pass B: recompute uhat, accumulate ----
#pragma unroll
      for (int kc = 0; kc < 5; ++kc) {
        const float cv = e[kc] * inv;
#pragma unroll
        for (int o = 0; o < 8; ++o) {
          const float4* w4 = reinterpret_cast<const float4*>(wp + (kc * 8 + o) * 32);
          acc[kc][o] =
              __builtin_fmaf(cv, dot8(w4[0], w4[1], cua, cub), acc[kc][o]);
        }
      }
    }
    __syncthreads(); // readers done with bufC; next DMA drained
    const float* tmp = bufC;
    bufC = bufN;
    bufN = const_cast<float*>(tmp);
    cua = nua;
    cub = nub;
  }

  // ---- cross-wave reduce: sAcc = wS buf0, stride 161 (2-way banks) ----
  float* sAcc = &wS[0][0];
#pragma unroll
  for (int r = 0; r < NW; ++r) {
    __syncthreads();
    if (wid == r) {
      float* dst = &sAcc[b_l * 161 + h * 80 + oh * 8];
      if (r == 0) {
#pragma unroll
        for (int kc = 0; kc < 5; ++kc)
#pragma unroll
          for (int o = 0; o < 8; ++o) dst[kc * 16 + o] = acc[kc][o];
      } else {
#pragma unroll
        for (int kc = 0; kc < 5; ++kc)
#pragma unroll
          for (int o = 0; o < 8; ++o) dst[kc * 16 + o] += acc[kc][o];
      }
    }
  }
  __syncthreads();
#pragma unroll
  for (int r = 0; r < 10; ++r) {
    const int g = tid + 256 * r; // 2560
    const int bl = g / 160, rem = g - 160 * bl;
    atomicAdd(&sOut[(size_t)(b0 + bl) * ROW + rem], sAcc[bl * 161 + rem]);
  }
}

__global__ __launch_bounds__(256) void k_out(const float* __restrict__ s,
                                             float* __restrict__ out) {
  const int g = blockIdx.x * 256 + threadIdx.x; // [0, 2560) = (b,c)
  const int b = g / 10, c = g - 10 * b;
  const float* sp = s + (size_t)b * ROW + c * 16;
  float sq = 0.f;
#pragma unroll
  for (int o = 0; o < On; ++o) { const float xx = sp[o]; sq += xx * xx; }
  const float fac = (sq / (1.f + sq)) / sqrtf(sq + 1e-9f);
  float* op = out + (size_t)b * ROW + c * 16;
#pragma unroll
  for (int o = 0; o < On; ++o) op[o] = fac * sp[o];
}

extern "C" void kernel_launch(void* const* d_in, const int* in_sizes, int n_in,
                              void* d_out, int out_size, void* d_ws, size_t ws_size,
                              hipStream_t stream) {
  (void)in_sizes; (void)n_in; (void)out_size;
  const float* u = (const float*)d_in[0];
  const float* W = (const float*)d_in[1];
  float* out = (float*)d_out;
  float* s1 = (float*)d_ws;            // [256][160] fp32
  float* s2 = s1 + (size_t)Bn * ROW;
  float* s3 = s2 + (size_t)Bn * ROW;
  float* lg = s3 + (size_t)Bn * ROW;   // [2048][256][10] fp32, 21MB
  float* Wp = lg + (size_t)Pn * Bn * Cn; // permuted W, 10.5MB
  const size_t need = ((size_t)3 * Bn * ROW + (size_t)Pn * Bn * Cn +
                       (size_t)Pn * Cn * On * In) * sizeof(float);
  if (ws_size < need) return;
  hipMemsetAsync(d_ws, 0, (size_t)3 * Bn * ROW * sizeof(float), stream);
  k_perm<<<Pn, 256, 0, stream>>>(W, Wp);
  k_cap<0><<<GRID, TPB, 0, stream>>>(u, Wp, s1, s1, lg);
  k_cap<1><<<GRID, TPB, 0, stream>>>(u, Wp, s1, s2, lg);
  k_cap<2><<<GRID, TPB, 0, stream>>>(u, Wp, s2, s3, lg);
  k_out<<<10, 256, 0, stream>>>(s3, out);
}

// Round 5
// 293.528 us; speedup vs baseline: 1.9468x; 1.0328x over previous
//
#include <hip/hip_runtime.h>

// CapsNet dynamic routing, B=256, P=2048, C=10, OUT=16, IN=8, 3 iters.
// R11: scalar-pipe W. R10 was issue-bound (118us/dispatch, VALU 45%, HBM 4%):
// every W operand made an LDS round-trip (160 ds_read_b128/thread/chunk, read
// twice by the A/B recompute) behind a per-chunk DMA-drain barrier.
// New mapping: wave = (h,oh), lane = b_l (BT=64). W slice per (p,wave) is
// WAVE-UNIFORM -> k_perm lays it contiguous (320 floats) and the compiler
// emits s_loads: W arrives as SGPR operands to v_fma, zero LDS, zero vector
// traffic. Single pass per p: uh[5][8]+acc[5][8]+v[5][8] in regs (~190 VGPR
// < 256 cap, all statically indexed - no R9 spill mode). v computed
// per-thread from sPrev (no vL). Softmax: 5 partial logits through a tiny
// double-buffered LDS exchange (stride 5 = conflict-free, ONE barrier per p,
// zero barriers in MODE0), then each thread redundantly softmaxes all 10 c's
// in-registers. s-reduce: arena-stage (stride 161) -> coalesced fp32 atomics.
// Passes: K<0>: s1=sum_p uhat; K<1>: v1=squash(.1*s1), lg2=uhat.v1 -> global,
// s2+=softmax(lg2)*uhat; K<2>: v2=squash(s2), lg3=lg2+uhat.v2, s3+=...;
// k_out: squash(s3).

#define Bn 256
#define Pn 2048
#define Cn 10
#define On 16
#define In 8
#define ROW 160
#define BT 64
#define PPB 16
#define TPB 256
#define NBT (Bn / BT)     // 4
#define NPT (Pn / PPB)    // 128
#define GRID (NBT * NPT)  // 512

// ---- one-time W permutation: Wp[p][g][kc][o][i], g = h*2+oh.
// Per (p, wave) slice = 320 contiguous floats -> s_load_dwordx16 friendly.
__global__ __launch_bounds__(256) void k_perm(const float* __restrict__ W,
                                              float* __restrict__ Wp) {
  const int p = blockIdx.x;
  const float* src = W + (size_t)p * 1280;
  float* dst = Wp + (size_t)p * 1280;
#pragma unroll
  for (int r = 0; r < 5; ++r) {
    const int w = threadIdx.x + 256 * r;
    const int g = w / 320, rm = w - 320 * g;
    const int kc = rm >> 6, r2 = rm & 63;
    const int o = r2 >> 3, i = r2 & 7;
    const int h = g >> 1, oh = g & 1;
    dst[w] = src[((h * 5 + kc) * 16 + oh * 8 + o) * 8 + i];
  }
}

template <int MODE>
__global__ __launch_bounds__(TPB, 2) void k_cap(const float* __restrict__ u,
                                                const float* __restrict__ Wp,
                                                const float* __restrict__ sPrev,
                                                float* __restrict__ sOut,
                                                float* __restrict__ lg) {
  // arena: main loop = lgx[2][4g][64b][5] (2560 floats); tail = sAcc[64][161]
  __shared__ float arena[BT * 161]; // 41216 B -> LDS allows 3 blocks/CU
  const int x = blockIdx.x;
  const int bt = x >> 7;   // 4 b-tiles
  const int pt = x & 127;  // 128 p-tiles; bt-sharers of a p-tile on one XCD
  const int tid = threadIdx.x;
  const int g = __builtin_amdgcn_readfirstlane(tid >> 6); // wave id = h*2+oh
  const int h = g >> 1, oh = g & 1;
  const int b_l = tid & 63;
  const int b = bt * BT + b_l;
  const int p0 = pt * PPB;

  // wave-uniform W base -> scalar loads
  const float* wp_s = Wp + ((size_t)p0 * 4 + g) * 320;

  // ---- v slice in registers (per-thread squash of sPrev; once per dispatch)
  float v[5][8];
  if (MODE >= 1) {
    const float scale = (MODE == 1) ? 0.1f : 1.0f;
    const float4* sp = reinterpret_cast<const float4*>(sPrev + (size_t)b * ROW);
#pragma unroll
    for (int kc = 0; kc < 5; ++kc) {
      const int c = h * 5 + kc;
      const float4 q0 = sp[c * 4 + 0], q1 = sp[c * 4 + 1];
      const float4 q2 = sp[c * 4 + 2], q3 = sp[c * 4 + 3];
      float sq = q0.x * q0.x + q0.y * q0.y + q0.z * q0.z + q0.w * q0.w;
      sq += q1.x * q1.x + q1.y * q1.y + q1.z * q1.z + q1.w * q1.w;
      sq += q2.x * q2.x + q2.y * q2.y + q2.z * q2.z + q2.w * q2.w;
      sq += q3.x * q3.x + q3.y * q3.y + q3.z * q3.z + q3.w * q3.w;
      sq *= scale * scale;
      const float fac = scale * (sq / (1.f + sq)) / sqrtf(sq + 1e-9f);
      const float4 qa = oh ? q2 : q0;
      const float4 qb = oh ? q3 : q1;
      v[kc][0] = fac * qa.x; v[kc][1] = fac * qa.y;
      v[kc][2] = fac * qa.z; v[kc][3] = fac * qa.w;
      v[kc][4] = fac * qb.x; v[kc][5] = fac * qb.y;
      v[kc][6] = fac * qb.z; v[kc][7] = fac * qb.w;
    }
  }

  float acc[5][8];
#pragma unroll
  for (int kc = 0; kc < 5; ++kc)
#pragma unroll
    for (int o = 0; o < 8; ++o) acc[kc][o] = 0.f;

  const float* urow = u + ((size_t)b * Pn + p0) * In;
  float4 cua, cub;
  {
    const float4* up = reinterpret_cast<const float4*>(urow);
    cua = up[0];
    cub = up[1];
  }

  for (int ip = 0; ip < PPB; ++ip) {
    // prefetch next p's u (named regs, static)
    float4 nua = cua, nub = cub;
    if (ip + 1 < PPB) {
      const float4* up = reinterpret_cast<const float4*>(urow + (ip + 1) * In);
      nua = up[0];
      nub = up[1];
    }
    const int p = p0 + ip;
    float lf[10];
    if (MODE == 2) { // issue early; latency hides under the dot block
      const float* lrow = lg + ((size_t)p * Bn + b) * Cn;
#pragma unroll
      for (int c = 0; c < 10; ++c) lf[c] = lrow[c];
    } else if (MODE == 1) {
#pragma unroll
      for (int c = 0; c < 10; ++c) lf[c] = 0.f;
    }
    const float uu[8] = {cua.x, cua.y, cua.z, cua.w, cub.x, cub.y, cub.z, cub.w};
    const float* wq = wp_s + ip * 1280; // scalar pointer

    float uh[5][8];
#pragma unroll
    for (int kc = 0; kc < 5; ++kc)
#pragma unroll
      for (int o = 0; o < 8; ++o) {
        const float* w8 = wq + kc * 64 + o * 8; // s_load operands
        float d = w8[0] * uu[0];
#pragma unroll
        for (int i = 1; i < 8; ++i) d = __builtin_fmaf(w8[i], uu[i], d);
        uh[kc][o] = d;
      }

    if (MODE == 0) {
#pragma unroll
      for (int kc = 0; kc < 5; ++kc)
#pragma unroll
        for (int o = 0; o < 8; ++o) acc[kc][o] += uh[kc][o];
    } else {
      // partial logits for this (h,oh) quarter
      float lp[5];
#pragma unroll
      for (int kc = 0; kc < 5; ++kc) {
        float ls = 0.f;
#pragma unroll
        for (int o = 0; o < 8; ++o) ls = __builtin_fmaf(uh[kc][o], v[kc][o], ls);
        lp[kc] = ls;
      }
      // exchange: lgx[(ip&1)][g][b_l][5]; stride 5 -> conflict-free
      float* lx = arena + (ip & 1) * 1280;
#pragma unroll
      for (int kc = 0; kc < 5; ++kc) lx[(g * 64 + b_l) * 5 + kc] = lp[kc];
      __syncthreads(); // double-buffered -> one barrier per p
#pragma unroll
      for (int c = 0; c < 10; ++c) {
        const int hh = c / 5, cc = c - 5 * (c / 5); // static after unroll
        lf[c] += lx[((hh * 2 + 0) * 64 + b_l) * 5 + cc] +
                 lx[((hh * 2 + 1) * 64 + b_l) * 5 + cc];
      }
      if (MODE == 1) {
        if (g == 0) { // wave-uniform branch; coalesced 40B/lane
          float* lrow = lg + ((size_t)p * Bn + b) * Cn;
#pragma unroll
          for (int c = 0; c < 10; ++c) lrow[c] = lf[c];
        }
      }
      // softmax over all 10 in-thread (redundant x4, cheap)
      float m = lf[0];
#pragma unroll
      for (int c = 1; c < 10; ++c) m = fmaxf(m, lf[c]);
      float ss = 0.f;
#pragma unroll
      for (int c = 0; c < 10; ++c) {
        lf[c] = __expf(lf[c] - m);
        ss += lf[c];
      }
      const float inv = 1.f / ss;
#pragma unroll
      for (int kc = 0; kc < 5; ++kc) {
        const float cv = lf[h * 5 + kc] * inv;
#pragma unroll
        for (int o = 0; o < 8; ++o)
          acc[kc][o] = __builtin_fmaf(cv, uh[kc][o], acc[kc][o]);
      }
    }
    cua = nua;
    cub = nub;
  }

  // ---- stage to arena (stride 161: lanes conflict-free) + coalesced atomics
  __syncthreads(); // last lgx reads done before arena reuse
  float* sA = arena;
#pragma unroll
  for (int kc = 0; kc < 5; ++kc)
#pragma unroll
    for (int o = 0; o < 8; ++o)
      sA[b_l * 161 + (h * 5 + kc) * 16 + oh * 8 + o] = acc[kc][o];
  __syncthreads();
#pragma unroll
  for (int r = 0; r < 40; ++r) {
    const int gi = tid + 256 * r; // 10240 cells, consecutive addresses
    const int bl = gi / 160, rem = gi - 160 * bl;
    atomicAdd(&sOut[(size_t)(bt * BT + bl) * ROW + rem], sA[bl * 161 + rem]);
  }
}

__global__ __launch_bounds__(256) void k_out(const float* __restrict__ s,
                                             float* __restrict__ out) {
  const int gi = blockIdx.x * 256 + threadIdx.x; // [0, 2560) = (b,c)
  const int b = gi / 10, c = gi - 10 * b;
  const float* sp = s + (size_t)b * ROW + c * 16;
  float sq = 0.f;
#pragma unroll
  for (int o = 0; o < On; ++o) { const float xx = sp[o]; sq += xx * xx; }
  const float fac = (sq / (1.f + sq)) / sqrtf(sq + 1e-9f);
  float* op = out + (size_t)b * ROW + c * 16;
#pragma unroll
  for (int o = 0; o < On; ++o) op[o] = fac * sp[o];
}

extern "C" void kernel_launch(void* const* d_in, const int* in_sizes, int n_in,
                              void* d_out, int out_size, void* d_ws, size_t ws_size,
                              hipStream_t stream) {
  (void)in_sizes; (void)n_in; (void)out_size;
  const float* u = (const float*)d_in[0];
  const float* W = (const float*)d_in[1];
  float* out = (float*)d_out;
  float* s1 = (float*)d_ws;              // [256][160] fp32
  float* s2 = s1 + (size_t)Bn * ROW;
  float* s3 = s2 + (size_t)Bn * ROW;
  float* lg = s3 + (size_t)Bn * ROW;     // [2048][256][10] fp32, 21MB
  float* Wp = lg + (size_t)Pn * Bn * Cn; // permuted W, 10.5MB
  const size_t need = ((size_t)3 * Bn * ROW + (size_t)Pn * Bn * Cn +
                       (size_t)Pn * Cn * On * In) * sizeof(float);
  if (ws_size < need) return;
  hipMemsetAsync(d_ws, 0, (size_t)3 * Bn * ROW * sizeof(float), stream);
  k_perm<<<Pn, 256, 0, stream>>>(W, Wp);
  k_cap<0><<<GRID, TPB, 0, stream>>>(u, Wp, s1, s1, lg);
  k_cap<1><<<GRID, TPB, 0, stream>>>(u, Wp, s1, s2, lg);
  k_cap<2><<<GRID, TPB, 0, stream>>>(u, Wp, s2, s3, lg);
  k_out<<<10, 256, 0, stream>>>(s3, out);
}